// Round 1
// baseline (237.668 us; speedup 1.0000x reference)
//
#include <hip/hip_runtime.h>

// LIF scan: u = 0.5*u + x_t; o = (u > 1); u = 0 where spiked.
// x: [B=32, T=128, N=8192] fp32; out same shape, values in {0.0f, 1.0f}.
// Memory-bound: 268 MB total traffic -> ~43 us floor at 6.3 TB/s.

constexpr int B  = 32;
constexpr int T  = 128;
constexpr int N  = 8192;
constexpr int N4 = N / 4;          // float4 granularity: 2048

__global__ __launch_bounds__(256) void lif_kernel(const float4* __restrict__ x,
                                                  float4* __restrict__ out) {
    int idx = blockIdx.x * blockDim.x + threadIdx.x;   // [0, B*N4)
    int b = idx >> 11;             // idx / N4   (N4 == 2048)
    int n = idx & (N4 - 1);        // idx % N4
    size_t base = (size_t)b * T * N4 + n;
    const float4* xp = x   + base;
    float4*       op = out + base;

    float ux = 0.f, uy = 0.f, uz = 0.f, uw = 0.f;
    #pragma unroll 8
    for (int t = 0; t < T; ++t) {
        float4 xt = xp[(size_t)t * N4];
        float4 o;
        ux = 0.5f * ux + xt.x;  o.x = (ux > 1.0f) ? 1.0f : 0.0f;  ux = (ux > 1.0f) ? 0.0f : ux;
        uy = 0.5f * uy + xt.y;  o.y = (uy > 1.0f) ? 1.0f : 0.0f;  uy = (uy > 1.0f) ? 0.0f : uy;
        uz = 0.5f * uz + xt.z;  o.z = (uz > 1.0f) ? 1.0f : 0.0f;  uz = (uz > 1.0f) ? 0.0f : uz;
        uw = 0.5f * uw + xt.w;  o.w = (uw > 1.0f) ? 1.0f : 0.0f;  uw = (uw > 1.0f) ? 0.0f : uw;
        op[(size_t)t * N4] = o;
    }
}

extern "C" void kernel_launch(void* const* d_in, const int* in_sizes, int n_in,
                              void* d_out, int out_size, void* d_ws, size_t ws_size,
                              hipStream_t stream) {
    const float4* x  = (const float4*)d_in[0];
    float4*      out = (float4*)d_out;
    int total = B * N4;                         // 65536 threads
    lif_kernel<<<total / 256, 256, 0, stream>>>(x, out);
}

// Round 2
// 236.515 us; speedup vs baseline: 1.0049x; 1.0049x over previous
//
#include <hip/hip_runtime.h>

// LIF scan: u = 0.5*u + x_t; o = (u > 1); u = 0 where spiked.
// x: [B=32, T=128, N=8192] fp32; out same shape, values in {0.0f, 1.0f}.
//
// R1 lesson: float4-per-thread left only 256 blocks = 1 block/CU (9% occ,
// 2.4 TB/s). Recurrence is sequential in T only, so max independent chains
// = B*N = 262144. Scalar thread per chain -> 1024 blocks = 4/CU = 16 waves/CU.

constexpr int B = 32;
constexpr int T = 128;
constexpr int N = 8192;

__global__ __launch_bounds__(256) void lif_kernel(const float* __restrict__ x,
                                                  float* __restrict__ out) {
    int idx = blockIdx.x * blockDim.x + threadIdx.x;   // [0, B*N)
    int b = idx >> 13;             // idx / N   (N == 8192)
    int n = idx & (N - 1);         // idx % N
    size_t base = (size_t)b * T * N + n;
    const float* xp = x   + base;
    float*       op = out + base;

    float u = 0.f;
    #pragma unroll 8
    for (int t = 0; t < T; ++t) {
        float xt = xp[(size_t)t * N];
        u = 0.5f * u + xt;
        float o = (u > 1.0f) ? 1.0f : 0.0f;
        u = (u > 1.0f) ? 0.0f : u;
        op[(size_t)t * N] = o;
    }
}

extern "C" void kernel_launch(void* const* d_in, const int* in_sizes, int n_in,
                              void* d_out, int out_size, void* d_ws, size_t ws_size,
                              hipStream_t stream) {
    const float* x  = (const float*)d_in[0];
    float*      out = (float*)d_out;
    int total = B * N;                           // 262144 threads
    lif_kernel<<<total / 256, 256, 0, stream>>>(x, out);
}